// Round 14
// baseline (235.505 us; speedup 1.0000x reference)
//
#include <hip/hip_runtime.h>

constexpr int H = 256, MSGC = 64;
constexpr float LN_EPS = 1e-5f;
// fold 1/sqrt(16) AND log2(e) into q so softmax exps are single v_exp_f32 (exp2)
constexpr float QSCALE = 0.25f * 1.4426950408889634f;

typedef __attribute__((ext_vector_type(8))) short bf16x8;
typedef __attribute__((ext_vector_type(4))) float f32x4;

#if __has_builtin(__builtin_amdgcn_exp2f)
__device__ __forceinline__ float fexp2(float x) { return __builtin_amdgcn_exp2f(x); }
#else
__device__ __forceinline__ float fexp2(float x) { return exp2f(x); }
#endif

__device__ inline ushort f2bf(float x) {
    union { float f; unsigned u; } v; v.f = x;
    unsigned r = v.u + 0x7fffu + ((v.u >> 16) & 1u);
    return (ushort)(r >> 16);
}
__device__ inline float bf2f(ushort h) {
    union { unsigned u; float f; } v; v.u = ((unsigned)h) << 16;
    return v.f;
}
__device__ inline unsigned cvt_pk_u32(float a, float b) {
    unsigned r;
    asm("v_cvt_pk_bf16_f32 %0, %1, %2" : "=v"(r) : "v"(a), "v"(b));
    return r;
}
__device__ inline bf16x8 pack_bf16x8(float4 f0, float4 f1) {
    union { unsigned u[4]; bf16x8 v; } cv;
    cv.u[0] = cvt_pk_u32(f0.x, f0.y);
    cv.u[1] = cvt_pk_u32(f0.z, f0.w);
    cv.u[2] = cvt_pk_u32(f1.x, f1.y);
    cv.u[3] = cvt_pk_u32(f1.z, f1.w);
    return cv.v;
}

// ---------------- prep: fragment-pack ALL weights (proj: 48 units; aggln: 160 units) ----------------
__global__ __launch_bounds__(256) void prep_kernel(
    const float* __restrict__ Wm, const float* __restrict__ Wk,
    const float* __restrict__ Wq, const float* __restrict__ Wa,
    ushort* __restrict__ Wph, ushort* __restrict__ Wpl,
    ushort* __restrict__ Wfh, ushort* __restrict__ Wfl)
{
    const int t = threadIdx.x, b = blockIdx.x;
    if (b < 48) {
        const int tile = b >> 3, kc = b & 7;
#pragma unroll
        for (int j2 = 0; j2 < 2; ++j2) {
            const int idx = t * 2 + j2;
            const int l = idx >> 3, e = idx & 7;
            const int col = tile * 16 + (l & 15);
            const int k = kc * 32 + (l >> 4) * 8 + e;
            float v;
            if (col < 64)      v = Wm[(size_t)col * H + k];
            else if (col < 80) v = Wk[(size_t)(col - 64) * H + k];
            else               v = QSCALE * Wq[(size_t)(col - 80) * H + k];
            ushort hi = f2bf(v);
            Wph[(size_t)b * 512 + idx] = hi;
            Wpl[(size_t)b * 512 + idx] = f2bf(v - bf2f(hi));
        }
    } else {
        const int unit = b - 48;
        const int ctg = unit / 10, kc = unit % 10;
#pragma unroll
        for (int j2 = 0; j2 < 2; ++j2) {
            const int idx = t * 2 + j2;
            const int l = idx >> 3, e = idx & 7;
            const int col = ctg * 16 + (l & 15);
            const int k = kc * 32 + (l >> 4) * 8 + e;
            const float v = Wa[(size_t)col * 320 + k];
            ushort hi = f2bf(v);
            Wfh[(size_t)unit * 512 + idx] = hi;
            Wfl[(size_t)unit * 512 + idx] = f2bf(v - bf2f(hi));
        }
    }
}

// ---------------- proj (MFMA): 16 rows/block, 2 waves, dual-split bf16, K=256 ----------------
__global__ __launch_bounds__(128) void proj_kernel(
    const float* __restrict__ h,
    const ushort* __restrict__ Wph, const ushort* __restrict__ Wpl,
    const float* __restrict__ bm, const float* __restrict__ bk, const float* __restrict__ bq,
    ushort* __restrict__ msgsF, ushort* __restrict__ kh, ushort* __restrict__ kl,
    ushort* __restrict__ qh, ushort* __restrict__ ql, int n)
{
    constexpr int AST = 264;
    __shared__ ushort Ahi[16 * AST];
    __shared__ ushort Alo[16 * AST];
    const int t = threadIdx.x, lane = t & 63, w = t >> 6;
    const int gq = lane >> 4, c = lane & 15;
    const int r0 = blockIdx.x * 16;
    const float4* hsrc = (const float4*)(h + (size_t)r0 * H);
#pragma unroll
    for (int u = 0; u < 8; ++u) {
        const int idx = t + 128 * u;
        const int row = idx >> 6, c4 = idx & 63;
        float4 v = hsrc[idx];
        ushort4 hi, lo;
        hi.x = f2bf(v.x); lo.x = f2bf(v.x - bf2f(hi.x));
        hi.y = f2bf(v.y); lo.y = f2bf(v.y - bf2f(hi.y));
        hi.z = f2bf(v.z); lo.z = f2bf(v.z - bf2f(hi.z));
        hi.w = f2bf(v.w); lo.w = f2bf(v.w - bf2f(hi.w));
        *(ushort4*)&Ahi[row * AST + c4 * 4] = hi;
        *(ushort4*)&Alo[row * AST + c4 * 4] = lo;
    }
    __syncthreads();
    f32x4 acc[3] = {{0,0,0,0},{0,0,0,0},{0,0,0,0}};
    for (int kc = 0; kc < 8; ++kc) {
        const bf16x8 afh = *(const bf16x8*)&Ahi[c * AST + kc * 32 + gq * 8];
        const bf16x8 afl = *(const bf16x8*)&Alo[c * AST + kc * 32 + gq * 8];
#pragma unroll
        for (int ct = 0; ct < 3; ++ct) {
            const int unit = (w * 3 + ct) * 8 + kc;
            const bf16x8 whi = *(const bf16x8*)(Wph + (size_t)unit * 512 + lane * 8);
            const bf16x8 wlo = *(const bf16x8*)(Wpl + (size_t)unit * 512 + lane * 8);
            acc[ct] = __builtin_amdgcn_mfma_f32_16x16x32_bf16(afh, whi, acc[ct], 0, 0, 0);
            acc[ct] = __builtin_amdgcn_mfma_f32_16x16x32_bf16(afh, wlo, acc[ct], 0, 0, 0);
            acc[ct] = __builtin_amdgcn_mfma_f32_16x16x32_bf16(afl, whi, acc[ct], 0, 0, 0);
        }
    }
#pragma unroll
    for (int ct = 0; ct < 3; ++ct) {
        const int tile = w * 3 + ct;
        if (tile < 4) {
            const float bb = bm[tile * 16 + c];
#pragma unroll
            for (int r = 0; r < 4; ++r) {
                const int j = r0 + gq * 4 + r;
                const size_t idx = ((size_t)(j >> 5) * 4 + tile) * 512
                                 + ((j >> 3) & 3) * 128 + c * 8 + (j & 7);
                msgsF[idx] = f2bf(acc[ct][r] + bb);
            }
        } else if (tile == 4) {
            const float bb = bk[c];
#pragma unroll
            for (int r = 0; r < 4; ++r) {
                const int j = r0 + gq * 4 + r;
                const float v = acc[ct][r] + bb;
                const ushort hi = f2bf(v);
                kh[(size_t)j * 16 + c] = hi;
                kl[(size_t)j * 16 + c] = f2bf(v - bf2f(hi));
            }
        } else {
            const float bb = QSCALE * bq[c];
#pragma unroll
            for (int r = 0; r < 4; ++r) {
                const int j = r0 + gq * 4 + r;
                const float v = acc[ct][r] + bb;
                const ushort hi = f2bf(v);
                qh[(size_t)j * 16 + c] = hi;
                ql[(size_t)j * 16 + c] = f2bf(v - bf2f(hi));
            }
        }
    }
}

// ---------------- shared helpers for the attention kernels ----------------
__device__ __forceinline__ void loadK(bf16x8* dst, const ushort* __restrict__ kh,
                                      int j0, int g, int c) {
#pragma unroll
    for (int js = 0; js < 4; ++js)
        dst[js] = *(const bf16x8*)(kh + (size_t)(j0 + js * 16 + c) * 16 + 8 * (g & 1));
}

__device__ __forceinline__ void qk_tile(const bf16x8* b1s, const ushort* __restrict__ kl,
                                        int j0, int g, int c, bf16x8 a1, bf16x8 a2,
                                        const bf16x8 zer, f32x4* pd) {
    const f32x4 z4 = {0.f, 0.f, 0.f, 0.f};
    bf16x8 b2s[4];
#pragma unroll
    for (int js = 0; js < 4; ++js)
        b2s[js] = (g < 2) ? *(const bf16x8*)(kl + (size_t)(j0 + js * 16 + c) * 16 + 8 * g) : zer;
    __builtin_amdgcn_s_setprio(1);
#pragma unroll
    for (int js = 0; js < 4; ++js) {
        pd[js] = __builtin_amdgcn_mfma_f32_16x16x32_bf16(a1, b1s[js], z4, 0, 0, 0);
        pd[js] = __builtin_amdgcn_mfma_f32_16x16x32_bf16(a2, b2s[js], pd[js], 0, 0, 0);
    }
    __builtin_amdgcn_s_setprio(0);
}

__device__ __forceinline__ void pv_tile(const float* __restrict__ P,
                                        const ushort* __restrict__ msgsF,
                                        int j0, int g, int c, int w, int lane, f32x4* accv) {
#pragma unroll
    for (int ks = 0; ks < 2; ++ks) {
        const int arow = w * 16 + c;
        const int sw = (arow & 7) << 2;
        const int colb = ks * 32 + 8 * g;
        float4 f0 = *(const float4*)&P[arow * 64 + ((colb) ^ sw)];
        float4 f1 = *(const float4*)&P[arow * 64 + ((colb + 4) ^ sw)];
        bf16x8 af = pack_bf16x8(f0, f1);
        const size_t mbase = ((size_t)(j0 >> 5) + ks) * 4;
        __builtin_amdgcn_s_setprio(1);
#pragma unroll
        for (int mt = 0; mt < 4; ++mt) {
            bf16x8 bfr = *((const bf16x8*)(msgsF + (mbase + mt) * 512) + lane);
            accv[mt] = __builtin_amdgcn_mfma_f32_16x16x32_bf16(af, bfr, accv[mt], 0, 0, 0);
        }
        __builtin_amdgcn_s_setprio(0);
    }
}

__device__ __forceinline__ void expstore(const f32x4* pd, float* Pbuf, float* l,
                                         int w, int g, int c) {
#pragma unroll
    for (int js = 0; js < 4; ++js)
#pragma unroll
        for (int r = 0; r < 4; ++r) {
            const int row = w * 16 + g * 4 + r;
            const float pp = fexp2(pd[js][r]);
            l[r] += pp;
            Pbuf[row * 64 + ((js * 16 + c) ^ ((row & 7) << 2))] = pp;
        }
}

__device__ __forceinline__ void expstore_n(const f32x4* pd, float* Pbuf, const float* rinv,
                                           int w, int g, int c) {
#pragma unroll
    for (int js = 0; js < 4; ++js)
#pragma unroll
        for (int r = 0; r < 4; ++r) {
            const int row = w * 16 + g * 4 + r;
            const float pp = fexp2(pd[js][r]) * rinv[r];
            Pbuf[row * 64 + ((js * 16 + c) ^ ((row & 7) << 2))] = pp;
        }
}

__device__ __forceinline__ void attn_write4(const float* __restrict__ Pbuf,
                                            float* __restrict__ attn,
                                            int i0, int j0, int n, int lane, int w) {
    const int c4 = lane & 15;
#pragma unroll
    for (int u = 0; u < 4; ++u) {
        const int row = w * 16 + u * 4 + (lane >> 4);
        const int sw = (row & 7) << 2;
        f32x4 v = *(const f32x4*)&Pbuf[row * 64 + ((c4 * 4) ^ sw)];
        __builtin_nontemporal_store(v, (f32x4*)(attn + (size_t)(i0 + row) * n + j0 + c4 * 4));
    }
}

// ---------------- flash1: round-1 attention; f32 P double-buffered, PV lagged one tile ----------------
__global__ __launch_bounds__(256, 4) void flash1_kernel(
    const ushort* __restrict__ qh, const ushort* __restrict__ ql,
    const ushort* __restrict__ kh, const ushort* __restrict__ kl,
    const ushort* __restrict__ msgsF,
    float* __restrict__ aggO, float* __restrict__ aggL, int n)
{
    __shared__ float P0[64 * 64];
    __shared__ float P1[64 * 64];
    const int t = threadIdx.x, lane = t & 63, w = t >> 6;
    const int g = lane >> 4, c = lane & 15;
    const int i0 = blockIdx.x * 64;
    bf16x8 zer = {0,0,0,0,0,0,0,0};
    f32x4 z4 = {0.f, 0.f, 0.f, 0.f};
    const ushort* qsrc = (g < 2) ? qh : ql;
    bf16x8 a1 = *(const bf16x8*)(qsrc + (size_t)(i0 + w * 16 + c) * 16 + 8 * (g & 1));
    bf16x8 a2 = (g < 2) ? a1 : zer;
    float l[4] = {0.f, 0.f, 0.f, 0.f};
    f32x4 accv[4] = {z4, z4, z4, z4};
    const int nj = n / 8, jb = blockIdx.y * nj;
    bf16x8 bA[4], bB[4];
    loadK(bA, kh, jb, g, c);
    loadK(bB, kh, jb + 64, g, c);
    {
        f32x4 pd[4];
        qk_tile(bA, kl, jb, g, c, a1, a2, zer, pd);
        expstore(pd, P0, l, w, g, c);
    }
    loadK(bA, kh, jb + 128, g, c);
    {
        f32x4 pd[4];
        qk_tile(bB, kl, jb + 64, g, c, a1, a2, zer, pd);
        pv_tile(P0, msgsF, jb, g, c, w, lane, accv);
        expstore(pd, P1, l, w, g, c);
    }
    for (int p = 1; p < 8; ++p) {
        const int tA = jb + p * 128, tB = tA + 64;
        loadK(bB, kh, tB, g, c);
        {
            f32x4 pd[4];
            qk_tile(bA, kl, tA, g, c, a1, a2, zer, pd);
            pv_tile(P1, msgsF, tA - 64, g, c, w, lane, accv);
            expstore(pd, P0, l, w, g, c);
        }
        loadK(bA, kh, (p < 7) ? tA + 128 : tB, g, c);
        {
            f32x4 pd[4];
            qk_tile(bB, kl, tB, g, c, a1, a2, zer, pd);
            pv_tile(P0, msgsF, tA, g, c, w, lane, accv);
            expstore(pd, P1, l, w, g, c);
        }
    }
    pv_tile(P1, msgsF, jb + nj - 64, g, c, w, lane, accv);
#pragma unroll
    for (int r = 0; r < 4; ++r)
#pragma unroll
        for (int d2 = 1; d2 < 16; d2 <<= 1) l[r] += __shfl_xor(l[r], d2, 64);
#pragma unroll
    for (int mt = 0; mt < 4; ++mt)
#pragma unroll
        for (int r = 0; r < 4; ++r)
            aggO[((size_t)blockIdx.y * n + i0 + w * 16 + g * 4 + r) * MSGC + mt * 16 + c] = accv[mt][r];
    if (c == 0) {
#pragma unroll
        for (int r = 0; r < 4; ++r)
            aggL[(size_t)blockIdx.y * n + i0 + w * 16 + g * 4 + r] = l[r];
    }
}

// ---------------- stats (round 2): row sums of exp2(s); j-split 16 for occupancy ----------------
__global__ __launch_bounds__(256, 4) void stats_kernel(
    const ushort* __restrict__ qh, const ushort* __restrict__ ql,
    const ushort* __restrict__ kh, const ushort* __restrict__ kl,
    float* __restrict__ rowl_p, int n)
{
    const int t = threadIdx.x, lane = t & 63, w = t >> 6;
    const int g = lane >> 4, c = lane & 15;
    const int iq = blockIdx.x * 64 + w * 16 + c;
    bf16x8 zer = {0,0,0,0,0,0,0,0};
    const ushort* qsrc = (g < 2) ? qh : ql;
    bf16x8 a1 = *(const bf16x8*)(qsrc + (size_t)iq * 16 + 8 * (g & 1));
    bf16x8 a2 = (g < 2) ? a1 : zer;
    const int nj = n / 16, jb = blockIdx.y * nj;   // 8 tiles of 64
    float l[4] = {0.f, 0.f, 0.f, 0.f};
    bf16x8 bA[4], bB[4];
    loadK(bA, kh, jb, g, c);
    for (int p = 0; p < 4; ++p) {
        const int t0 = jb + p * 128, t1 = t0 + 64;
        const int t2 = (p < 3) ? t0 + 128 : t1;
        loadK(bB, kh, t1, g, c);
        {
            f32x4 pd[4];
            qk_tile(bA, kl, t0, g, c, a1, a2, zer, pd);
#pragma unroll
            for (int js = 0; js < 4; ++js)
#pragma unroll
                for (int r = 0; r < 4; ++r) l[r] += fexp2(pd[js][r]);
        }
        loadK(bA, kh, t2, g, c);
        {
            f32x4 pd[4];
            qk_tile(bB, kl, t1, g, c, a1, a2, zer, pd);
#pragma unroll
            for (int js = 0; js < 4; ++js)
#pragma unroll
                for (int r = 0; r < 4; ++r) l[r] += fexp2(pd[js][r]);
        }
    }
#pragma unroll
    for (int r = 0; r < 4; ++r)
#pragma unroll
        for (int d2 = 1; d2 < 16; d2 <<= 1) l[r] += __shfl_xor(l[r], d2, 64);
    if (c == 0) {
        const int q0 = blockIdx.x * 64 + w * 16 + g * 4;
#pragma unroll
        for (int r = 0; r < 4; ++r)
            rowl_p[(size_t)blockIdx.y * n + q0 + r] = l[r];
    }
}

// ---------------- pass2 (round 2): f32 P double-buffered; attn write + PV lagged one tile ----------------
__global__ __launch_bounds__(256, 4) void pass2_kernel(
    const ushort* __restrict__ qh, const ushort* __restrict__ ql,
    const ushort* __restrict__ kh, const ushort* __restrict__ kl,
    const ushort* __restrict__ msgsF, const float* __restrict__ rowl_p,
    float* __restrict__ aggO, float* __restrict__ attn, int n)
{
    __shared__ float P0[64 * 64];
    __shared__ float P1[64 * 64];
    const int t = threadIdx.x, lane = t & 63, w = t >> 6;
    const int g = lane >> 4, c = lane & 15;
    const int i0 = blockIdx.x * 64;
    bf16x8 zer = {0,0,0,0,0,0,0,0};
    f32x4 z4 = {0.f, 0.f, 0.f, 0.f};
    const ushort* qsrc = (g < 2) ? qh : ql;
    bf16x8 a1 = *(const bf16x8*)(qsrc + (size_t)(i0 + w * 16 + c) * 16 + 8 * (g & 1));
    bf16x8 a2 = (g < 2) ? a1 : zer;
    float rinv[4];
#pragma unroll
    for (int r = 0; r < 4; ++r) {
        const int q = i0 + w * 16 + g * 4 + r;
        float L = 0.f;
#pragma unroll
        for (int p = 0; p < 16; ++p) L += rowl_p[(size_t)p * n + q];
        rinv[r] = 1.f / L;
    }
    f32x4 accv[4] = {z4, z4, z4, z4};
    const int nj = n / 8, jb = blockIdx.y * nj;
    bf16x8 bA[4], bB[4];
    loadK(bA, kh, jb, g, c);
    loadK(bB, kh, jb + 64, g, c);
    {
        f32x4 pd[4];
        qk_tile(bA, kl, jb, g, c, a1, a2, zer, pd);
        expstore_n(pd, P0, rinv, w, g, c);
    }
    loadK(bA, kh, jb + 128, g, c);
    {
        f32x4 pd[4];
        qk_tile(bB, kl, jb + 64, g, c, a1, a2, zer, pd);
        attn_write4(P0, attn, i0, jb, n, lane, w);
        pv_tile(P0, msgsF, jb, g, c, w, lane, accv);
        expstore_n(pd, P1, rinv, w, g, c);
    }
    for (int p = 1; p < 8; ++p) {
        const int tA = jb + p * 128, tB = tA + 64;
        loadK(bB, kh, tB, g, c);
        {
            f32x4 pd[4];
            qk_tile(bA, kl, tA, g, c, a1, a2, zer, pd);
            attn_write4(P1, attn, i0, tA - 64, n, lane, w);
            pv_tile(P1, msgsF, tA - 64, g, c, w, lane, accv);
            expstore_n(pd, P0, rinv, w, g, c);
        }
        loadK(bA, kh, (p < 7) ? tA + 128 : tB, g, c);
        {
            f32x4 pd[4];
            qk_tile(bB, kl, tB, g, c, a1, a2, zer, pd);
            attn_write4(P0, attn, i0, tA, n, lane, w);
            pv_tile(P0, msgsF, tA, g, c, w, lane, accv);
            expstore_n(pd, P1, rinv, w, g, c);
        }
    }
    attn_write4(P1, attn, i0, jb + nj - 64, n, lane, w);
    pv_tile(P1, msgsF, jb + nj - 64, g, c, w, lane, accv);
#pragma unroll
    for (int mt = 0; mt < 4; ++mt)
#pragma unroll
        for (int r = 0; r < 4; ++r) {
            const int row = w * 16 + g * 4 + r;
            aggO[((size_t)blockIdx.y * n + i0 + row) * MSGC + mt * 16 + c] = accv[mt][r];
        }
}

// ---------------- aggln (MFMA): 8 rows/block for 2x block-parallelism ----------------
template <bool FLASH>
__global__ __launch_bounds__(256) void aggln_kernel(
    const float* __restrict__ h, const float* __restrict__ aggO,
    const float* __restrict__ aggL,
    const ushort* __restrict__ Wfh, const ushort* __restrict__ Wfl,
    const float* __restrict__ ba,
    const float* __restrict__ gg, const float* __restrict__ bb,
    float* __restrict__ hout, int n)
{
    constexpr int AST = 328;
    __shared__ ushort Ahi[16 * AST];
    __shared__ ushort Alo[16 * AST];
    __shared__ float Linv[8];
    __shared__ float red1[16][4], red2[16][4];
    const int t = threadIdx.x, lane = t & 63, w = t >> 6;
    const int gq = lane >> 4, c = lane & 15;
    const int r0 = blockIdx.x * 8;
    const float4* hsrc = (const float4*)(h + (size_t)r0 * H);
#pragma unroll
    for (int u = 0; u < 4; ++u) {
        const int idx = t + 256 * u;
        const int row = idx >> 6, c4 = idx & 63;
        float4 v = (row < 8) ? hsrc[idx] : make_float4(0.f, 0.f, 0.f, 0.f);
        ushort4 hi, lo;
        hi.x = f2bf(v.x); lo.x = f2bf(v.x - bf2f(hi.x));
        hi.y = f2bf(v.y); lo.y = f2bf(v.y - bf2f(hi.y));
        hi.z = f2bf(v.z); lo.z = f2bf(v.z - bf2f(hi.z));
        hi.w = f2bf(v.w); lo.w = f2bf(v.w - bf2f(hi.w));
        *(ushort4*)&Ahi[row * AST + c4 * 4] = hi;
        *(ushort4*)&Alo[row * AST + c4 * 4] = lo;
    }
    if (FLASH && t < 8) {
        float L = 0.f;
#pragma unroll
        for (int p = 0; p < 8; ++p) L += aggL[(size_t)p * n + r0 + t];
        Linv[t] = 1.f / L;
    }
    __syncthreads();
    if (t < 128) {
        const int row = t >> 4, c4 = t & 15;
        float4 s = {0.f, 0.f, 0.f, 0.f};
#pragma unroll
        for (int p = 0; p < 8; ++p) {
            const float4 v = *(const float4*)(aggO + (size_t)p * n * MSGC
                               + (size_t)(r0 + row) * MSGC + c4 * 4);
            s.x += v.x; s.y += v.y; s.z += v.z; s.w += v.w;
        }
        if (FLASH) { const float li = Linv[row]; s.x *= li; s.y *= li; s.z *= li; s.w *= li; }
        ushort4 hi, lo;
        hi.x = f2bf(s.x); lo.x = f2bf(s.x - bf2f(hi.x));
        hi.y = f2bf(s.y); lo.y = f2bf(s.y - bf2f(hi.y));
        hi.z = f2bf(s.z); lo.z = f2bf(s.z - bf2f(hi.z));
        hi.w = f2bf(s.w); lo.w = f2bf(s.w - bf2f(hi.w));
        *(ushort4*)&Ahi[row * AST + 256 + c4 * 4] = hi;
        *(ushort4*)&Alo[row * AST + 256 + c4 * 4] = lo;
    } else {
        const int row = 8 + ((t - 128) >> 4), c4 = (t - 128) & 15;
        const ushort4 zz = {0, 0, 0, 0};
        *(ushort4*)&Ahi[row * AST + 256 + c4 * 4] = zz;
        *(ushort4*)&Alo[row * AST + 256 + c4 * 4] = zz;
    }
    __syncthreads();
    f32x4 acc[4] = {{0,0,0,0},{0,0,0,0},{0,0,0,0},{0,0,0,0}};
    for (int kc = 0; kc < 10; ++kc) {
        const bf16x8 afh = *(const bf16x8*)&Ahi[c * AST + kc * 32 + gq * 8];
        const bf16x8 afl = *(const bf16x8*)&Alo[c * AST + kc * 32 + gq * 8];
#pragma unroll
        for (int ct = 0; ct < 4; ++ct) {
            const int ctg = w * 4 + ct;
            const bf16x8 whi = *(const bf16x8*)(Wfh + ((size_t)(ctg * 10 + kc)) * 512 + lane * 8);
            const bf16x8 wlo = *(const bf16x8*)(Wfl + ((size_t)(ctg * 10 + kc)) * 512 + lane * 8);
            acc[ct] = __builtin_amdgcn_mfma_f32_16x16x32_bf16(afh, whi, acc[ct], 0, 0, 0);
            acc[ct] = __builtin_amdgcn_mfma_f32_16x16x32_bf16(afh, wlo, acc[ct], 0, 0, 0);
            acc[ct] = __builtin_amdgcn_mfma_f32_16x16x32_bf16(afl, whi, acc[ct], 0, 0, 0);
        }
    }
    float bav[4], gv[4], bv[4];
#pragma unroll
    for (int ct = 0; ct < 4; ++ct) {
        const int col = w * 64 + ct * 16 + c;
        bav[ct] = ba[col]; gv[ct] = gg[col]; bv[ct] = bb[col];
    }
#pragma unroll
    for (int ct = 0; ct < 4; ++ct) {
        acc[ct][0] += bav[ct]; acc[ct][1] += bav[ct];
        acc[ct][2] += bav[ct]; acc[ct][3] += bav[ct];
    }
#pragma unroll
    for (int r = 0; r < 4; ++r) {
        float s1 = 0.f, s2 = 0.f;
#pragma unroll
        for (int ct = 0; ct < 4; ++ct) { const float v = acc[ct][r]; s1 += v; s2 += v * v; }
#pragma unroll
        for (int d = 1; d < 16; d <<= 1) { s1 += __shfl_xor(s1, d, 64); s2 += __shfl_xor(s2, d, 64); }
        if (c == 0) { red1[gq * 4 + r][w] = s1; red2[gq * 4 + r][w] = s2; }
    }
    __syncthreads();
    if (gq < 2) {
#pragma unroll
        for (int r = 0; r < 4; ++r) {
            const int row = gq * 4 + r;
            const float s1 = red1[row][0] + red1[row][1] + red1[row][2] + red1[row][3];
            const float s2 = red2[row][0] + red2[row][1] + red2[row][2] + red2[row][3];
            const float mu = s1 * (1.f / 256.f);
            const float var = s2 * (1.f / 256.f) - mu * mu;
            const float rs = rsqrtf(var + LN_EPS);
#pragma unroll
            for (int ct = 0; ct < 4; ++ct) {
                float o = (acc[ct][r] - mu) * rs * gv[ct] + bv[ct];
                hout[(size_t)(r0 + row) * H + w * 64 + ct * 16 + c] = fmaxf(o, 0.f);
            }
        }
    }
}

extern "C" void kernel_launch(void* const* d_in, const int* in_sizes, int n_in,
                              void* d_out, int out_size, void* d_ws, size_t ws_size,
                              hipStream_t stream)
{
    const float* hs = (const float*)d_in[0];
    const float* Wm = (const float*)d_in[1];
    const float* bm = (const float*)d_in[2];
    const float* Wk = (const float*)d_in[3];
    const float* bk = (const float*)d_in[4];
    const float* Wq = (const float*)d_in[5];
    const float* bq = (const float*)d_in[6];
    const float* Wa = (const float*)d_in[7];
    const float* ba = (const float*)d_in[8];
    const float* lg = (const float*)d_in[9];
    const float* lb = (const float*)d_in[10];
    const int n = in_sizes[0] / H;         // 8192

    char* wp = (char*)d_ws;
    auto alloc = [&](size_t bytes) { void* p = (void*)wp; wp += (bytes + 255) & ~(size_t)255; return p; };
    float*  h2     = (float*)alloc((size_t)n * H * 4);
    ushort* qh     = (ushort*)alloc((size_t)n * 16 * 2);
    ushort* ql     = (ushort*)alloc((size_t)n * 16 * 2);
    ushort* kh     = (ushort*)alloc((size_t)n * 16 * 2);
    ushort* kl     = (ushort*)alloc((size_t)n * 16 * 2);
    ushort* msgsF  = (ushort*)alloc((size_t)MSGC * n * 2);
    float*  rowl_p = (float*)alloc((size_t)16 * n * 4);
    float*  aggO   = (float*)alloc((size_t)8 * n * MSGC * 4);
    float*  aggL   = (float*)alloc((size_t)8 * n * 4);
    ushort* Wph    = (ushort*)alloc((size_t)48 * 512 * 2);
    ushort* Wpl    = (ushort*)alloc((size_t)48 * 512 * 2);
    ushort* Wfh    = (ushort*)alloc((size_t)160 * 512 * 2);
    ushort* Wfl    = (ushort*)alloc((size_t)160 * 512 * 2);

    float* hOut = (float*)d_out;
    float* attn = hOut + (size_t)n * H;

    prep_kernel<<<208, 256, 0, stream>>>(Wm, Wk, Wq, Wa, Wph, Wpl, Wfh, Wfl);

    // round 1: proj (MFMA) -> flash (unnormalized O + L) -> aggln (normalizes)
    proj_kernel<<<n / 16, 128, 0, stream>>>(hs, Wph, Wpl, bm, bk, bq, msgsF, kh, kl, qh, ql, n);
    flash1_kernel<<<dim3(n / 64, 8), 256, 0, stream>>>(qh, ql, kh, kl, msgsF,
                                                       aggO, aggL, n);
    aggln_kernel<true><<<n / 8, 256, 0, stream>>>(hs, aggO, aggL, Wfh, Wfl,
                                                  ba, lg, lb, h2, n);
    // round 2: proj -> stats (row sums, j-split 16) -> pass2 (normalized attn + PV) -> aggln
    proj_kernel<<<n / 16, 128, 0, stream>>>(h2, Wph, Wpl, bm, bk, bq, msgsF, kh, kl, qh, ql, n);
    stats_kernel<<<dim3(n / 64, 16), 256, 0, stream>>>(qh, ql, kh, kl, rowl_p, n);
    pass2_kernel<<<dim3(n / 64, 8), 256, 0, stream>>>(qh, ql, kh, kl, msgsF,
                                                      rowl_p, aggO, attn, n);
    aggln_kernel<false><<<n / 8, 256, 0, stream>>>(h2, aggO, aggL, Wfh, Wfl,
                                                   ba, lg, lb, hOut, n);
}

// Round 15
// 231.660 us; speedup vs baseline: 1.0166x; 1.0166x over previous
//
#include <hip/hip_runtime.h>

constexpr int H = 256, MSGC = 64;
constexpr float LN_EPS = 1e-5f;
// fold 1/sqrt(16) AND log2(e) into q so softmax exps are single v_exp_f32 (exp2)
constexpr float QSCALE = 0.25f * 1.4426950408889634f;

typedef __attribute__((ext_vector_type(8))) short bf16x8;
typedef __attribute__((ext_vector_type(4))) float f32x4;

#if __has_builtin(__builtin_amdgcn_exp2f)
__device__ __forceinline__ float fexp2(float x) { return __builtin_amdgcn_exp2f(x); }
#else
__device__ __forceinline__ float fexp2(float x) { return exp2f(x); }
#endif

__device__ inline ushort f2bf(float x) {
    union { float f; unsigned u; } v; v.f = x;
    unsigned r = v.u + 0x7fffu + ((v.u >> 16) & 1u);
    return (ushort)(r >> 16);
}
__device__ inline float bf2f(ushort h) {
    union { unsigned u; float f; } v; v.u = ((unsigned)h) << 16;
    return v.f;
}
__device__ inline unsigned cvt_pk_u32(float a, float b) {
    unsigned r;
    asm("v_cvt_pk_bf16_f32 %0, %1, %2" : "=v"(r) : "v"(a), "v"(b));
    return r;
}
__device__ inline bf16x8 pack_bf16x8(float4 f0, float4 f1) {
    union { unsigned u[4]; bf16x8 v; } cv;
    cv.u[0] = cvt_pk_u32(f0.x, f0.y);
    cv.u[1] = cvt_pk_u32(f0.z, f0.w);
    cv.u[2] = cvt_pk_u32(f1.x, f1.y);
    cv.u[3] = cvt_pk_u32(f1.z, f1.w);
    return cv.v;
}

// ---------------- prep: fragment-pack ALL weights (proj: 48 units; aggln: 160 units) ----------------
__global__ __launch_bounds__(256) void prep_kernel(
    const float* __restrict__ Wm, const float* __restrict__ Wk,
    const float* __restrict__ Wq, const float* __restrict__ Wa,
    ushort* __restrict__ Wph, ushort* __restrict__ Wpl,
    ushort* __restrict__ Wfh, ushort* __restrict__ Wfl)
{
    const int t = threadIdx.x, b = blockIdx.x;
    if (b < 48) {
        const int tile = b >> 3, kc = b & 7;
#pragma unroll
        for (int j2 = 0; j2 < 2; ++j2) {
            const int idx = t * 2 + j2;
            const int l = idx >> 3, e = idx & 7;
            const int col = tile * 16 + (l & 15);
            const int k = kc * 32 + (l >> 4) * 8 + e;
            float v;
            if (col < 64)      v = Wm[(size_t)col * H + k];
            else if (col < 80) v = Wk[(size_t)(col - 64) * H + k];
            else               v = QSCALE * Wq[(size_t)(col - 80) * H + k];
            ushort hi = f2bf(v);
            Wph[(size_t)b * 512 + idx] = hi;
            Wpl[(size_t)b * 512 + idx] = f2bf(v - bf2f(hi));
        }
    } else {
        const int unit = b - 48;
        const int ctg = unit / 10, kc = unit % 10;
#pragma unroll
        for (int j2 = 0; j2 < 2; ++j2) {
            const int idx = t * 2 + j2;
            const int l = idx >> 3, e = idx & 7;
            const int col = ctg * 16 + (l & 15);
            const int k = kc * 32 + (l >> 4) * 8 + e;
            const float v = Wa[(size_t)col * 320 + k];
            ushort hi = f2bf(v);
            Wfh[(size_t)unit * 512 + idx] = hi;
            Wfl[(size_t)unit * 512 + idx] = f2bf(v - bf2f(hi));
        }
    }
}

// ---------------- proj (MFMA): 16 rows/block, 2 waves, dual-split bf16, K=256 ----------------
__global__ __launch_bounds__(128) void proj_kernel(
    const float* __restrict__ h,
    const ushort* __restrict__ Wph, const ushort* __restrict__ Wpl,
    const float* __restrict__ bm, const float* __restrict__ bk, const float* __restrict__ bq,
    ushort* __restrict__ msgsF, ushort* __restrict__ kh, ushort* __restrict__ kl,
    ushort* __restrict__ qh, ushort* __restrict__ ql, int n)
{
    constexpr int AST = 264;
    __shared__ ushort Ahi[16 * AST];
    __shared__ ushort Alo[16 * AST];
    const int t = threadIdx.x, lane = t & 63, w = t >> 6;
    const int gq = lane >> 4, c = lane & 15;
    const int r0 = blockIdx.x * 16;
    const float4* hsrc = (const float4*)(h + (size_t)r0 * H);
#pragma unroll
    for (int u = 0; u < 8; ++u) {
        const int idx = t + 128 * u;
        const int row = idx >> 6, c4 = idx & 63;
        float4 v = hsrc[idx];
        ushort4 hi, lo;
        hi.x = f2bf(v.x); lo.x = f2bf(v.x - bf2f(hi.x));
        hi.y = f2bf(v.y); lo.y = f2bf(v.y - bf2f(hi.y));
        hi.z = f2bf(v.z); lo.z = f2bf(v.z - bf2f(hi.z));
        hi.w = f2bf(v.w); lo.w = f2bf(v.w - bf2f(hi.w));
        *(ushort4*)&Ahi[row * AST + c4 * 4] = hi;
        *(ushort4*)&Alo[row * AST + c4 * 4] = lo;
    }
    __syncthreads();
    f32x4 acc[3] = {{0,0,0,0},{0,0,0,0},{0,0,0,0}};
    for (int kc = 0; kc < 8; ++kc) {
        const bf16x8 afh = *(const bf16x8*)&Ahi[c * AST + kc * 32 + gq * 8];
        const bf16x8 afl = *(const bf16x8*)&Alo[c * AST + kc * 32 + gq * 8];
#pragma unroll
        for (int ct = 0; ct < 3; ++ct) {
            const int unit = (w * 3 + ct) * 8 + kc;
            const bf16x8 whi = *(const bf16x8*)(Wph + (size_t)unit * 512 + lane * 8);
            const bf16x8 wlo = *(const bf16x8*)(Wpl + (size_t)unit * 512 + lane * 8);
            acc[ct] = __builtin_amdgcn_mfma_f32_16x16x32_bf16(afh, whi, acc[ct], 0, 0, 0);
            acc[ct] = __builtin_amdgcn_mfma_f32_16x16x32_bf16(afh, wlo, acc[ct], 0, 0, 0);
            acc[ct] = __builtin_amdgcn_mfma_f32_16x16x32_bf16(afl, whi, acc[ct], 0, 0, 0);
        }
    }
#pragma unroll
    for (int ct = 0; ct < 3; ++ct) {
        const int tile = w * 3 + ct;
        if (tile < 4) {
            const float bb = bm[tile * 16 + c];
#pragma unroll
            for (int r = 0; r < 4; ++r) {
                const int j = r0 + gq * 4 + r;
                const size_t idx = ((size_t)(j >> 5) * 4 + tile) * 512
                                 + ((j >> 3) & 3) * 128 + c * 8 + (j & 7);
                msgsF[idx] = f2bf(acc[ct][r] + bb);
            }
        } else if (tile == 4) {
            const float bb = bk[c];
#pragma unroll
            for (int r = 0; r < 4; ++r) {
                const int j = r0 + gq * 4 + r;
                const float v = acc[ct][r] + bb;
                const ushort hi = f2bf(v);
                kh[(size_t)j * 16 + c] = hi;
                kl[(size_t)j * 16 + c] = f2bf(v - bf2f(hi));
            }
        } else {
            const float bb = QSCALE * bq[c];
#pragma unroll
            for (int r = 0; r < 4; ++r) {
                const int j = r0 + gq * 4 + r;
                const float v = acc[ct][r] + bb;
                const ushort hi = f2bf(v);
                qh[(size_t)j * 16 + c] = hi;
                ql[(size_t)j * 16 + c] = f2bf(v - bf2f(hi));
            }
        }
    }
}

// ---------------- shared helpers for the attention kernels ----------------
__device__ __forceinline__ void loadK(bf16x8* dst, const ushort* __restrict__ kh,
                                      int j0, int g, int c) {
#pragma unroll
    for (int js = 0; js < 4; ++js)
        dst[js] = *(const bf16x8*)(kh + (size_t)(j0 + js * 16 + c) * 16 + 8 * (g & 1));
}

__device__ __forceinline__ void qk_tile(const bf16x8* b1s, const ushort* __restrict__ kl,
                                        int j0, int g, int c, bf16x8 a1, bf16x8 a2,
                                        const bf16x8 zer, f32x4* pd) {
    const f32x4 z4 = {0.f, 0.f, 0.f, 0.f};
    bf16x8 b2s[4];
#pragma unroll
    for (int js = 0; js < 4; ++js)
        b2s[js] = (g < 2) ? *(const bf16x8*)(kl + (size_t)(j0 + js * 16 + c) * 16 + 8 * g) : zer;
    __builtin_amdgcn_s_setprio(1);
#pragma unroll
    for (int js = 0; js < 4; ++js) {
        pd[js] = __builtin_amdgcn_mfma_f32_16x16x32_bf16(a1, b1s[js], z4, 0, 0, 0);
        pd[js] = __builtin_amdgcn_mfma_f32_16x16x32_bf16(a2, b2s[js], pd[js], 0, 0, 0);
    }
    __builtin_amdgcn_s_setprio(0);
}

// two q-bands sharing the same K fragments (stats): 2x ILP per wave
__device__ __forceinline__ void qk_tile2(const bf16x8* b1s, const ushort* __restrict__ kl,
                                         int j0, int g, int c,
                                         bf16x8 a1, bf16x8 a2, bf16x8 a1b, bf16x8 a2b,
                                         const bf16x8 zer, f32x4* pd, f32x4* pdb) {
    const f32x4 z4 = {0.f, 0.f, 0.f, 0.f};
    bf16x8 b2s[4];
#pragma unroll
    for (int js = 0; js < 4; ++js)
        b2s[js] = (g < 2) ? *(const bf16x8*)(kl + (size_t)(j0 + js * 16 + c) * 16 + 8 * g) : zer;
    __builtin_amdgcn_s_setprio(1);
#pragma unroll
    for (int js = 0; js < 4; ++js) {
        pd[js]  = __builtin_amdgcn_mfma_f32_16x16x32_bf16(a1,  b1s[js], z4, 0, 0, 0);
        pdb[js] = __builtin_amdgcn_mfma_f32_16x16x32_bf16(a1b, b1s[js], z4, 0, 0, 0);
        pd[js]  = __builtin_amdgcn_mfma_f32_16x16x32_bf16(a2,  b2s[js], pd[js], 0, 0, 0);
        pdb[js] = __builtin_amdgcn_mfma_f32_16x16x32_bf16(a2b, b2s[js], pdb[js], 0, 0, 0);
    }
    __builtin_amdgcn_s_setprio(0);
}

__device__ __forceinline__ void pv_tile(const float* __restrict__ P,
                                        const ushort* __restrict__ msgsF,
                                        int j0, int g, int c, int w, int lane, f32x4* accv) {
#pragma unroll
    for (int ks = 0; ks < 2; ++ks) {
        const int arow = w * 16 + c;
        const int sw = (arow & 7) << 2;
        const int colb = ks * 32 + 8 * g;
        float4 f0 = *(const float4*)&P[arow * 64 + ((colb) ^ sw)];
        float4 f1 = *(const float4*)&P[arow * 64 + ((colb + 4) ^ sw)];
        bf16x8 af = pack_bf16x8(f0, f1);
        const size_t mbase = ((size_t)(j0 >> 5) + ks) * 4;
        __builtin_amdgcn_s_setprio(1);
#pragma unroll
        for (int mt = 0; mt < 4; ++mt) {
            bf16x8 bfr = *((const bf16x8*)(msgsF + (mbase + mt) * 512) + lane);
            accv[mt] = __builtin_amdgcn_mfma_f32_16x16x32_bf16(af, bfr, accv[mt], 0, 0, 0);
        }
        __builtin_amdgcn_s_setprio(0);
    }
}

__device__ __forceinline__ void expstore(const f32x4* pd, float* Pbuf, float* l,
                                         int w, int g, int c) {
#pragma unroll
    for (int js = 0; js < 4; ++js)
#pragma unroll
        for (int r = 0; r < 4; ++r) {
            const int row = w * 16 + g * 4 + r;
            const float pp = fexp2(pd[js][r]);
            l[r] += pp;
            Pbuf[row * 64 + ((js * 16 + c) ^ ((row & 7) << 2))] = pp;
        }
}

__device__ __forceinline__ void expstore_n(const f32x4* pd, float* Pbuf, const float* rinv,
                                           int w, int g, int c) {
#pragma unroll
    for (int js = 0; js < 4; ++js)
#pragma unroll
        for (int r = 0; r < 4; ++r) {
            const int row = w * 16 + g * 4 + r;
            const float pp = fexp2(pd[js][r]) * rinv[r];
            Pbuf[row * 64 + ((js * 16 + c) ^ ((row & 7) << 2))] = pp;
        }
}

__device__ __forceinline__ void attn_write4(const float* __restrict__ Pbuf,
                                            float* __restrict__ attn,
                                            int i0, int j0, int n, int lane, int w) {
    const int c4 = lane & 15;
#pragma unroll
    for (int u = 0; u < 4; ++u) {
        const int row = w * 16 + u * 4 + (lane >> 4);
        const int sw = (row & 7) << 2;
        f32x4 v = *(const f32x4*)&Pbuf[row * 64 + ((c4 * 4) ^ sw)];
        __builtin_nontemporal_store(v, (f32x4*)(attn + (size_t)(i0 + row) * n + j0 + c4 * 4));
    }
}

// ---------------- flash1: round-1 attention; f32 P double-buffered, PV lagged one tile ----------------
__global__ __launch_bounds__(256, 4) void flash1_kernel(
    const ushort* __restrict__ qh, const ushort* __restrict__ ql,
    const ushort* __restrict__ kh, const ushort* __restrict__ kl,
    const ushort* __restrict__ msgsF,
    float* __restrict__ aggO, float* __restrict__ aggL, int n)
{
    __shared__ float P0[64 * 64];
    __shared__ float P1[64 * 64];
    const int t = threadIdx.x, lane = t & 63, w = t >> 6;
    const int g = lane >> 4, c = lane & 15;
    const int i0 = blockIdx.x * 64;
    bf16x8 zer = {0,0,0,0,0,0,0,0};
    f32x4 z4 = {0.f, 0.f, 0.f, 0.f};
    const ushort* qsrc = (g < 2) ? qh : ql;
    bf16x8 a1 = *(const bf16x8*)(qsrc + (size_t)(i0 + w * 16 + c) * 16 + 8 * (g & 1));
    bf16x8 a2 = (g < 2) ? a1 : zer;
    float l[4] = {0.f, 0.f, 0.f, 0.f};
    f32x4 accv[4] = {z4, z4, z4, z4};
    const int nj = n / 8, jb = blockIdx.y * nj;
    bf16x8 bA[4], bB[4];
    loadK(bA, kh, jb, g, c);
    loadK(bB, kh, jb + 64, g, c);
    {
        f32x4 pd[4];
        qk_tile(bA, kl, jb, g, c, a1, a2, zer, pd);
        expstore(pd, P0, l, w, g, c);
    }
    loadK(bA, kh, jb + 128, g, c);
    {
        f32x4 pd[4];
        qk_tile(bB, kl, jb + 64, g, c, a1, a2, zer, pd);
        pv_tile(P0, msgsF, jb, g, c, w, lane, accv);
        expstore(pd, P1, l, w, g, c);
    }
    for (int p = 1; p < 8; ++p) {
        const int tA = jb + p * 128, tB = tA + 64;
        loadK(bB, kh, tB, g, c);
        {
            f32x4 pd[4];
            qk_tile(bA, kl, tA, g, c, a1, a2, zer, pd);
            pv_tile(P1, msgsF, tA - 64, g, c, w, lane, accv);
            expstore(pd, P0, l, w, g, c);
        }
        loadK(bA, kh, (p < 7) ? tA + 128 : tB, g, c);
        {
            f32x4 pd[4];
            qk_tile(bB, kl, tB, g, c, a1, a2, zer, pd);
            pv_tile(P0, msgsF, tA, g, c, w, lane, accv);
            expstore(pd, P1, l, w, g, c);
        }
    }
    pv_tile(P1, msgsF, jb + nj - 64, g, c, w, lane, accv);
#pragma unroll
    for (int r = 0; r < 4; ++r)
#pragma unroll
        for (int d2 = 1; d2 < 16; d2 <<= 1) l[r] += __shfl_xor(l[r], d2, 64);
#pragma unroll
    for (int mt = 0; mt < 4; ++mt)
#pragma unroll
        for (int r = 0; r < 4; ++r)
            aggO[((size_t)blockIdx.y * n + i0 + w * 16 + g * 4 + r) * MSGC + mt * 16 + c] = accv[mt][r];
    if (c == 0) {
#pragma unroll
        for (int r = 0; r < 4; ++r)
            aggL[(size_t)blockIdx.y * n + i0 + w * 16 + g * 4 + r] = l[r];
    }
}

// ---------------- stats (round 2): 2-band (128 q-rows/block), shared K fragments ----------------
__global__ __launch_bounds__(256, 4) void stats_kernel(
    const ushort* __restrict__ qh, const ushort* __restrict__ ql,
    const ushort* __restrict__ kh, const ushort* __restrict__ kl,
    float* __restrict__ rowl_p, int n)
{
    const int t = threadIdx.x, lane = t & 63, w = t >> 6;
    const int g = lane >> 4, c = lane & 15;
    const int i0 = blockIdx.x * 128;
    bf16x8 zer = {0,0,0,0,0,0,0,0};
    const ushort* qsrc = (g < 2) ? qh : ql;
    bf16x8 a1  = *(const bf16x8*)(qsrc + (size_t)(i0 + w * 16 + c) * 16 + 8 * (g & 1));
    bf16x8 a1b = *(const bf16x8*)(qsrc + (size_t)(i0 + 64 + w * 16 + c) * 16 + 8 * (g & 1));
    bf16x8 a2  = (g < 2) ? a1  : zer;
    bf16x8 a2b = (g < 2) ? a1b : zer;
    const int nj = n / 16, jb = blockIdx.y * nj;   // 512 cols = 8 tiles of 64
    float l[4] = {0.f, 0.f, 0.f, 0.f}, lb[4] = {0.f, 0.f, 0.f, 0.f};
    bf16x8 bA[4], bB[4];
    loadK(bA, kh, jb, g, c);
    for (int p = 0; p < 4; ++p) {
        const int t0 = jb + p * 128, t1 = t0 + 64;
        const int t2 = (p < 3) ? t0 + 128 : t1;
        loadK(bB, kh, t1, g, c);
        {
            f32x4 pd[4], pdb[4];
            qk_tile2(bA, kl, t0, g, c, a1, a2, a1b, a2b, zer, pd, pdb);
#pragma unroll
            for (int js = 0; js < 4; ++js)
#pragma unroll
                for (int r = 0; r < 4; ++r) {
                    l[r]  += fexp2(pd[js][r]);
                    lb[r] += fexp2(pdb[js][r]);
                }
        }
        loadK(bA, kh, t2, g, c);
        {
            f32x4 pd[4], pdb[4];
            qk_tile2(bB, kl, t1, g, c, a1, a2, a1b, a2b, zer, pd, pdb);
#pragma unroll
            for (int js = 0; js < 4; ++js)
#pragma unroll
                for (int r = 0; r < 4; ++r) {
                    l[r]  += fexp2(pd[js][r]);
                    lb[r] += fexp2(pdb[js][r]);
                }
        }
    }
#pragma unroll
    for (int r = 0; r < 4; ++r)
#pragma unroll
        for (int d2 = 1; d2 < 16; d2 <<= 1) {
            l[r]  += __shfl_xor(l[r], d2, 64);
            lb[r] += __shfl_xor(lb[r], d2, 64);
        }
    if (c == 0) {
        const int q0 = i0 + w * 16 + g * 4;
#pragma unroll
        for (int r = 0; r < 4; ++r) {
            rowl_p[(size_t)blockIdx.y * n + q0 + r]      = l[r];
            rowl_p[(size_t)blockIdx.y * n + q0 + 64 + r] = lb[r];
        }
    }
}

// ---------------- pass2 (round 2): f32 P double-buffered; attn write + PV lagged one tile ----------------
__global__ __launch_bounds__(256, 4) void pass2_kernel(
    const ushort* __restrict__ qh, const ushort* __restrict__ ql,
    const ushort* __restrict__ kh, const ushort* __restrict__ kl,
    const ushort* __restrict__ msgsF, const float* __restrict__ rowl_p,
    float* __restrict__ aggO, float* __restrict__ attn, int n)
{
    __shared__ float P0[64 * 64];
    __shared__ float P1[64 * 64];
    const int t = threadIdx.x, lane = t & 63, w = t >> 6;
    const int g = lane >> 4, c = lane & 15;
    const int i0 = blockIdx.x * 64;
    bf16x8 zer = {0,0,0,0,0,0,0,0};
    f32x4 z4 = {0.f, 0.f, 0.f, 0.f};
    const ushort* qsrc = (g < 2) ? qh : ql;
    bf16x8 a1 = *(const bf16x8*)(qsrc + (size_t)(i0 + w * 16 + c) * 16 + 8 * (g & 1));
    bf16x8 a2 = (g < 2) ? a1 : zer;
    float rinv[4];
#pragma unroll
    for (int r = 0; r < 4; ++r) {
        const int q = i0 + w * 16 + g * 4 + r;
        float L = 0.f;
#pragma unroll
        for (int p = 0; p < 16; ++p) L += rowl_p[(size_t)p * n + q];
        rinv[r] = 1.f / L;
    }
    f32x4 accv[4] = {z4, z4, z4, z4};
    const int nj = n / 8, jb = blockIdx.y * nj;
    bf16x8 bA[4], bB[4];
    loadK(bA, kh, jb, g, c);
    loadK(bB, kh, jb + 64, g, c);
    {
        f32x4 pd[4];
        qk_tile(bA, kl, jb, g, c, a1, a2, zer, pd);
        expstore_n(pd, P0, rinv, w, g, c);
    }
    loadK(bA, kh, jb + 128, g, c);
    {
        f32x4 pd[4];
        qk_tile(bB, kl, jb + 64, g, c, a1, a2, zer, pd);
        attn_write4(P0, attn, i0, jb, n, lane, w);
        pv_tile(P0, msgsF, jb, g, c, w, lane, accv);
        expstore_n(pd, P1, rinv, w, g, c);
    }
    for (int p = 1; p < 8; ++p) {
        const int tA = jb + p * 128, tB = tA + 64;
        loadK(bB, kh, tB, g, c);
        {
            f32x4 pd[4];
            qk_tile(bA, kl, tA, g, c, a1, a2, zer, pd);
            attn_write4(P1, attn, i0, tA - 64, n, lane, w);
            pv_tile(P1, msgsF, tA - 64, g, c, w, lane, accv);
            expstore_n(pd, P0, rinv, w, g, c);
        }
        loadK(bA, kh, (p < 7) ? tA + 128 : tB, g, c);
        {
            f32x4 pd[4];
            qk_tile(bB, kl, tB, g, c, a1, a2, zer, pd);
            attn_write4(P0, attn, i0, tA, n, lane, w);
            pv_tile(P0, msgsF, tA, g, c, w, lane, accv);
            expstore_n(pd, P1, rinv, w, g, c);
        }
    }
    attn_write4(P1, attn, i0, jb + nj - 64, n, lane, w);
    pv_tile(P1, msgsF, jb + nj - 64, g, c, w, lane, accv);
#pragma unroll
    for (int mt = 0; mt < 4; ++mt)
#pragma unroll
        for (int r = 0; r < 4; ++r) {
            const int row = w * 16 + g * 4 + r;
            aggO[((size_t)blockIdx.y * n + i0 + row) * MSGC + mt * 16 + c] = accv[mt][r];
        }
}

// ---------------- aggln (MFMA): 8 rows/block for 2x block-parallelism ----------------
template <bool FLASH>
__global__ __launch_bounds__(256) void aggln_kernel(
    const float* __restrict__ h, const float* __restrict__ aggO,
    const float* __restrict__ aggL,
    const ushort* __restrict__ Wfh, const ushort* __restrict__ Wfl,
    const float* __restrict__ ba,
    const float* __restrict__ gg, const float* __restrict__ bb,
    float* __restrict__ hout, int n)
{
    constexpr int AST = 328;
    __shared__ ushort Ahi[16 * AST];
    __shared__ ushort Alo[16 * AST];
    __shared__ float Linv[8];
    __shared__ float red1[16][4], red2[16][4];
    const int t = threadIdx.x, lane = t & 63, w = t >> 6;
    const int gq = lane >> 4, c = lane & 15;
    const int r0 = blockIdx.x * 8;
    const float4* hsrc = (const float4*)(h + (size_t)r0 * H);
#pragma unroll
    for (int u = 0; u < 4; ++u) {
        const int idx = t + 256 * u;
        const int row = idx >> 6, c4 = idx & 63;
        float4 v = (row < 8) ? hsrc[idx] : make_float4(0.f, 0.f, 0.f, 0.f);
        ushort4 hi, lo;
        hi.x = f2bf(v.x); lo.x = f2bf(v.x - bf2f(hi.x));
        hi.y = f2bf(v.y); lo.y = f2bf(v.y - bf2f(hi.y));
        hi.z = f2bf(v.z); lo.z = f2bf(v.z - bf2f(hi.z));
        hi.w = f2bf(v.w); lo.w = f2bf(v.w - bf2f(hi.w));
        *(ushort4*)&Ahi[row * AST + c4 * 4] = hi;
        *(ushort4*)&Alo[row * AST + c4 * 4] = lo;
    }
    if (FLASH && t < 8) {
        float L = 0.f;
#pragma unroll
        for (int p = 0; p < 8; ++p) L += aggL[(size_t)p * n + r0 + t];
        Linv[t] = 1.f / L;
    }
    __syncthreads();
    if (t < 128) {
        const int row = t >> 4, c4 = t & 15;
        float4 s = {0.f, 0.f, 0.f, 0.f};
#pragma unroll
        for (int p = 0; p < 8; ++p) {
            const float4 v = *(const float4*)(aggO + (size_t)p * n * MSGC
                               + (size_t)(r0 + row) * MSGC + c4 * 4);
            s.x += v.x; s.y += v.y; s.z += v.z; s.w += v.w;
        }
        if (FLASH) { const float li = Linv[row]; s.x *= li; s.y *= li; s.z *= li; s.w *= li; }
        ushort4 hi, lo;
        hi.x = f2bf(s.x); lo.x = f2bf(s.x - bf2f(hi.x));
        hi.y = f2bf(s.y); lo.y = f2bf(s.y - bf2f(hi.y));
        hi.z = f2bf(s.z); lo.z = f2bf(s.z - bf2f(hi.z));
        hi.w = f2bf(s.w); lo.w = f2bf(s.w - bf2f(hi.w));
        *(ushort4*)&Ahi[row * AST + 256 + c4 * 4] = hi;
        *(ushort4*)&Alo[row * AST + 256 + c4 * 4] = lo;
    } else {
        const int row = 8 + ((t - 128) >> 4), c4 = (t - 128) & 15;
        const ushort4 zz = {0, 0, 0, 0};
        *(ushort4*)&Ahi[row * AST + 256 + c4 * 4] = zz;
        *(ushort4*)&Alo[row * AST + 256 + c4 * 4] = zz;
    }
    __syncthreads();
    f32x4 acc[4] = {{0,0,0,0},{0,0,0,0},{0,0,0,0},{0,0,0,0}};
    for (int kc = 0; kc < 10; ++kc) {
        const bf16x8 afh = *(const bf16x8*)&Ahi[c * AST + kc * 32 + gq * 8];
        const bf16x8 afl = *(const bf16x8*)&Alo[c * AST + kc * 32 + gq * 8];
#pragma unroll
        for (int ct = 0; ct < 4; ++ct) {
            const int ctg = w * 4 + ct;
            const bf16x8 whi = *(const bf16x8*)(Wfh + ((size_t)(ctg * 10 + kc)) * 512 + lane * 8);
            const bf16x8 wlo = *(const bf16x8*)(Wfl + ((size_t)(ctg * 10 + kc)) * 512 + lane * 8);
            acc[ct] = __builtin_amdgcn_mfma_f32_16x16x32_bf16(afh, whi, acc[ct], 0, 0, 0);
            acc[ct] = __builtin_amdgcn_mfma_f32_16x16x32_bf16(afh, wlo, acc[ct], 0, 0, 0);
            acc[ct] = __builtin_amdgcn_mfma_f32_16x16x32_bf16(afl, whi, acc[ct], 0, 0, 0);
        }
    }
    float bav[4], gv[4], bv[4];
#pragma unroll
    for (int ct = 0; ct < 4; ++ct) {
        const int col = w * 64 + ct * 16 + c;
        bav[ct] = ba[col]; gv[ct] = gg[col]; bv[ct] = bb[col];
    }
#pragma unroll
    for (int ct = 0; ct < 4; ++ct) {
        acc[ct][0] += bav[ct]; acc[ct][1] += bav[ct];
        acc[ct][2] += bav[ct]; acc[ct][3] += bav[ct];
    }
#pragma unroll
    for (int r = 0; r < 4; ++r) {
        float s1 = 0.f, s2 = 0.f;
#pragma unroll
        for (int ct = 0; ct < 4; ++ct) { const float v = acc[ct][r]; s1 += v; s2 += v * v; }
#pragma unroll
        for (int d = 1; d < 16; d <<= 1) { s1 += __shfl_xor(s1, d, 64); s2 += __shfl_xor(s2, d, 64); }
        if (c == 0) { red1[gq * 4 + r][w] = s1; red2[gq * 4 + r][w] = s2; }
    }
    __syncthreads();
    if (gq < 2) {
#pragma unroll
        for (int r = 0; r < 4; ++r) {
            const int row = gq * 4 + r;
            const float s1 = red1[row][0] + red1[row][1] + red1[row][2] + red1[row][3];
            const float s2 = red2[row][0] + red2[row][1] + red2[row][2] + red2[row][3];
            const float mu = s1 * (1.f / 256.f);
            const float var = s2 * (1.f / 256.f) - mu * mu;
            const float rs = rsqrtf(var + LN_EPS);
#pragma unroll
            for (int ct = 0; ct < 4; ++ct) {
                float o = (acc[ct][r] - mu) * rs * gv[ct] + bv[ct];
                hout[(size_t)(r0 + row) * H + w * 64 + ct * 16 + c] = fmaxf(o, 0.f);
            }
        }
    }
}

extern "C" void kernel_launch(void* const* d_in, const int* in_sizes, int n_in,
                              void* d_out, int out_size, void* d_ws, size_t ws_size,
                              hipStream_t stream)
{
    const float* hs = (const float*)d_in[0];
    const float* Wm = (const float*)d_in[1];
    const float* bm = (const float*)d_in[2];
    const float* Wk = (const float*)d_in[3];
    const float* bk = (const float*)d_in[4];
    const float* Wq = (const float*)d_in[5];
    const float* bq = (const float*)d_in[6];
    const float* Wa = (const float*)d_in[7];
    const float* ba = (const float*)d_in[8];
    const float* lg = (const float*)d_in[9];
    const float* lb = (const float*)d_in[10];
    const int n = in_sizes[0] / H;         // 8192

    char* wp = (char*)d_ws;
    auto alloc = [&](size_t bytes) { void* p = (void*)wp; wp += (bytes + 255) & ~(size_t)255; return p; };
    float*  h2     = (float*)alloc((size_t)n * H * 4);
    ushort* qh     = (ushort*)alloc((size_t)n * 16 * 2);
    ushort* ql     = (ushort*)alloc((size_t)n * 16 * 2);
    ushort* kh     = (ushort*)alloc((size_t)n * 16 * 2);
    ushort* kl     = (ushort*)alloc((size_t)n * 16 * 2);
    ushort* msgsF  = (ushort*)alloc((size_t)MSGC * n * 2);
    float*  rowl_p = (float*)alloc((size_t)16 * n * 4);
    float*  aggO   = (float*)alloc((size_t)8 * n * MSGC * 4);
    float*  aggL   = (float*)alloc((size_t)8 * n * 4);
    ushort* Wph    = (ushort*)alloc((size_t)48 * 512 * 2);
    ushort* Wpl    = (ushort*)alloc((size_t)48 * 512 * 2);
    ushort* Wfh    = (ushort*)alloc((size_t)160 * 512 * 2);
    ushort* Wfl    = (ushort*)alloc((size_t)160 * 512 * 2);

    float* hOut = (float*)d_out;
    float* attn = hOut + (size_t)n * H;

    prep_kernel<<<208, 256, 0, stream>>>(Wm, Wk, Wq, Wa, Wph, Wpl, Wfh, Wfl);

    // round 1: proj (MFMA) -> flash (unnormalized O + L) -> aggln (normalizes)
    proj_kernel<<<n / 16, 128, 0, stream>>>(hs, Wph, Wpl, bm, bk, bq, msgsF, kh, kl, qh, ql, n);
    flash1_kernel<<<dim3(n / 64, 8), 256, 0, stream>>>(qh, ql, kh, kl, msgsF,
                                                       aggO, aggL, n);
    aggln_kernel<true><<<n / 8, 256, 0, stream>>>(hs, aggO, aggL, Wfh, Wfl,
                                                  ba, lg, lb, h2, n);
    // round 2: proj -> stats (2-band, j-split 16) -> pass2 (normalized attn + PV) -> aggln
    proj_kernel<<<n / 16, 128, 0, stream>>>(h2, Wph, Wpl, bm, bk, bq, msgsF, kh, kl, qh, ql, n);
    stats_kernel<<<dim3(n / 128, 16), 256, 0, stream>>>(qh, ql, kh, kl, rowl_p, n);
    pass2_kernel<<<dim3(n / 64, 8), 256, 0, stream>>>(qh, ql, kh, kl, msgsF,
                                                      rowl_p, aggO, attn, n);
    aggln_kernel<false><<<n / 8, 256, 0, stream>>>(h2, aggO, aggL, Wfh, Wfl,
                                                   ba, lg, lb, hOut, n);
}